// Round 2
// baseline (2703.963 us; speedup 1.0000x reference)
//
#include <hip/hip_runtime.h>
#include <hip/hip_fp16.h>

#define B_ 256
#define T_ 1200
#define I_ 16
#define H_ 128

typedef __attribute__((ext_vector_type(2))) _Float16 h2;
typedef __attribute__((ext_vector_type(8))) _Float16 f16x8;

union f16x8u { f16x8 v; h2 h[4]; _Float16 s[8]; };

#if __has_builtin(__builtin_amdgcn_fdot2)
__device__ __forceinline__ float fdot2(h2 a, h2 b, float c) {
  return __builtin_amdgcn_fdot2(a, b, c, false);  // v_dot2_f32_f16
}
#else
__device__ __forceinline__ float fdot2(h2 a, h2 b, float c) {
  return fmaf((float)a.x, (float)b.x, fmaf((float)a.y, (float)b.y, c));
}
#endif

// Sum across the 8 lanes of an octet (c = tid&7). After xor1+xor2 the value
// is quad-uniform, so row_half_mirror (i -> 7-i, i.e. xor7) == xor4.
// All three levels run on the VALU DPP path (fused v_add_f32_dpp).
__device__ __forceinline__ float qsum8(float x) {
  x += __int_as_float(__builtin_amdgcn_update_dpp(0, __float_as_int(x), 0xB1, 0xF, 0xF, true));  // quad_perm xor1
  x += __int_as_float(__builtin_amdgcn_update_dpp(0, __float_as_int(x), 0x4E, 0xF, 0xF, true));  // quad_perm xor2
  x += __int_as_float(__builtin_amdgcn_update_dpp(0, __float_as_int(x), 0x141, 0xF, 0xF, true)); // row_half_mirror ~ xor4
  return x;
}

// Reduce octet-uniform values across the 8 octets of a wave.
// row_mirror (i -> 15-i, xor15) == xor8 given octet-uniform input.
__device__ __forceinline__ float ored(float x) {
  x += __int_as_float(__builtin_amdgcn_update_dpp(0, __float_as_int(x), 0x140, 0xF, 0xF, true)); // row_mirror ~ xor8
  x += __shfl_xor(x, 16);
  x += __shfl_xor(x, 32);
  return x;
}

__device__ __forceinline__ float sigm(float x) {
  return __builtin_amdgcn_rcpf(1.f + __expf(-x));
}
__device__ __forceinline__ float tanh_(float x) {
  return 1.f - 2.f * __builtin_amdgcn_rcpf(1.f + __expf(2.f * x));
}

// Fully fused 2-layer LSTM + linear head. One WG (1024 thr) per batch row.
// Octet owns h-index j (j = tid>>3); lane c = tid&7 holds k-slice [16c,16c+16)
// of W_hh0, W_ih1, W_hh1 rows {j, j+128, j+256, j+384} as fp16x2 in VGPRs
// (3 * 32 = 96 VGPRs). 1024 thr = 16 waves = 4 waves/SIMD forces the
// allocator to <=128 arch VGPRs AND uses the whole 512-reg unified file
// (no AGPR shadow space, no spill room needed: working set ~110 regs).
// W_ih0 slices + combined biases live in LDS (fp16), re-read each step
// (one broadcast ds_read_b128 each; __syncthreads keeps them un-hoisted).
// h state in tiny LDS double buffers (fp16). ZERO workspace. 2 barriers/step.
__global__ __launch_bounds__(1024, 4) void lstm_fused(
    const float* __restrict__ xin,
    const float* __restrict__ Wih0, const float* __restrict__ Whh0,
    const float* __restrict__ bih0, const float* __restrict__ bhh0,
    const float* __restrict__ Wih1, const float* __restrict__ Whh1,
    const float* __restrict__ bih1, const float* __restrict__ bhh1,
    const float* __restrict__ Wlin, const float* __restrict__ blin,
    float* __restrict__ out)
{
  __shared__ __align__(16) __half buf0[2][H_];    // layer-0 h, double buffered
  __shared__ __align__(16) __half buf1[2][H_];    // layer-1 h
  __shared__ __align__(16) float red[2][16];      // out-reduction per wave
  __shared__ __align__(16) h2 lwx[128][8][4];     // W_ih0 [j][c][q], 16 KB
  __shared__ __align__(16) __half lbh[128][8];    // bias [j][{q, 4+q}], 2 KB

  const int tid = threadIdx.x;
  const int c = tid & 7;
  const int j = tid >> 3;
  const int b = blockIdx.x;
  const int wv = tid >> 6;

  h2 w0[4][8], wi[4][8], wh[4][8];  // fp16x2 weight slices (96 VGPRs)

#pragma unroll
  for (int q = 0; q < 4; ++q) {
    const int g = q * H_ + j;
    const float* p0 = Whh0 + (size_t)g * H_ + c * 16;
    const float* p1 = Wih1 + (size_t)g * H_ + c * 16;
    const float* p2 = Whh1 + (size_t)g * H_ + c * 16;
#pragma unroll
    for (int i = 0; i < 4; ++i) {
      float4 v = *(const float4*)(p0 + 4 * i);
      w0[q][2*i].x   = (_Float16)v.x; w0[q][2*i].y   = (_Float16)v.y;
      w0[q][2*i+1].x = (_Float16)v.z; w0[q][2*i+1].y = (_Float16)v.w;
      v = *(const float4*)(p1 + 4 * i);
      wi[q][2*i].x   = (_Float16)v.x; wi[q][2*i].y   = (_Float16)v.y;
      wi[q][2*i+1].x = (_Float16)v.z; wi[q][2*i+1].y = (_Float16)v.w;
      v = *(const float4*)(p2 + 4 * i);
      wh[q][2*i].x   = (_Float16)v.x; wh[q][2*i].y   = (_Float16)v.y;
      wh[q][2*i+1].x = (_Float16)v.z; wh[q][2*i+1].y = (_Float16)v.w;
    }
    const float2 vx = *(const float2*)(Wih0 + (size_t)g * I_ + 2 * c);
    h2 t; t.x = (_Float16)vx.x; t.y = (_Float16)vx.y;
    lwx[j][c][q] = t;
  }
  if (tid < H_) {
#pragma unroll
    for (int q = 0; q < 4; ++q) {
      const int g = q * H_ + tid;
      lbh[tid][q]     = __float2half(bih0[g] + bhh0[g]);
      lbh[tid][4 + q] = __float2half(bih1[g] + bhh1[g]);
    }
    buf0[0][tid] = __float2half(0.f);
    buf1[0][tid] = __float2half(0.f);
  }
  const float wl = Wlin[j];  // head weight (octet-redundant; ored sums octets)
  const float bl = blin[0];

  float cst0 = 0.f, cst1 = 0.f;
  const float* xp = xin + (size_t)b * T_ * I_ + 2 * c;
  __syncthreads();

#pragma unroll 1
  for (int t = 0; t < T_; ++t) {
    const int rb = t & 1;
    // ---------------- layer 0 ----------------
    const float2 xv = *(const float2*)xp; xp += I_;            // issue early
    f16x8u wxu; wxu.v = *(const f16x8*)(&lwx[j][c][0]);        // 4 h2 (W_ih0)
    f16x8u bu;  bu.v  = *(const f16x8*)(&lbh[j][0]);           // 8 biases
    float a0 = 0.f, a1 = 0.f, a2 = 0.f, a3 = 0.f;
#pragma unroll
    for (int i = 0; i < 2; ++i) {
      f16x8u u; u.v = *(const f16x8*)(&buf0[rb][c * 16 + i * 8]);  // broadcast
#pragma unroll
      for (int p = 0; p < 4; ++p) {
        const h2 hv = u.h[p];
        a0 = fdot2(w0[0][4 * i + p], hv, a0);
        a1 = fdot2(w0[1][4 * i + p], hv, a1);
        a2 = fdot2(w0[2][4 * i + p], hv, a2);
        a3 = fdot2(w0[3][4 * i + p], hv, a3);
      }
    }
    h2 xa; xa.x = (_Float16)xv.x; xa.y = (_Float16)xv.y;
    a0 = fdot2(wxu.h[0], xa, a0);
    a1 = fdot2(wxu.h[1], xa, a1);
    a2 = fdot2(wxu.h[2], xa, a2);
    a3 = fdot2(wxu.h[3], xa, a3);
    {
      const float g0 = qsum8(a0) + (float)bu.s[0];
      const float g1 = qsum8(a1) + (float)bu.s[1];
      const float g2 = qsum8(a2) + (float)bu.s[2];
      const float g3 = qsum8(a3) + (float)bu.s[3];
      const float ig = sigm(g0), fg = sigm(g1), gg = tanh_(g2), og = sigm(g3);
      cst0 = fg * cst0 + ig * gg;
      const float h0v = og * tanh_(cst0);
      if (c == 0) buf0[rb ^ 1][j] = __float2half(h0v);
    }
    __syncthreads();
    // ---------------- layer 1 ----------------
    a0 = 0.f; a1 = 0.f; a2 = 0.f; a3 = 0.f;
#pragma unroll
    for (int i = 0; i < 2; ++i) {
      f16x8u u; u.v = *(const f16x8*)(&buf0[rb ^ 1][c * 16 + i * 8]);  // h0_t
#pragma unroll
      for (int p = 0; p < 4; ++p) {
        const h2 hv = u.h[p];
        a0 = fdot2(wi[0][4 * i + p], hv, a0);
        a1 = fdot2(wi[1][4 * i + p], hv, a1);
        a2 = fdot2(wi[2][4 * i + p], hv, a2);
        a3 = fdot2(wi[3][4 * i + p], hv, a3);
      }
    }
#pragma unroll
    for (int i = 0; i < 2; ++i) {
      f16x8u u; u.v = *(const f16x8*)(&buf1[rb][c * 16 + i * 8]);  // h1_{t-1}
#pragma unroll
      for (int p = 0; p < 4; ++p) {
        const h2 hv = u.h[p];
        a0 = fdot2(wh[0][4 * i + p], hv, a0);
        a1 = fdot2(wh[1][4 * i + p], hv, a1);
        a2 = fdot2(wh[2][4 * i + p], hv, a2);
        a3 = fdot2(wh[3][4 * i + p], hv, a3);
      }
    }
    const float g0 = qsum8(a0) + (float)bu.s[4];
    const float g1 = qsum8(a1) + (float)bu.s[5];
    const float g2 = qsum8(a2) + (float)bu.s[6];
    const float g3 = qsum8(a3) + (float)bu.s[7];
    const float ig = sigm(g0), fg = sigm(g1), gg = tanh_(g2), og = sigm(g3);
    cst1 = fg * cst1 + ig * gg;
    const float h1v = og * tanh_(cst1);
    if (c == 0) buf1[rb ^ 1][j] = __float2half(h1v);
    // fused relu + W_lin dot: h1v/wl octet-uniform; ored sums the 8 octets.
    float val = ored(fmaxf(h1v, 0.f) * wl);
    if ((tid & 63) == 0) red[rb][wv] = val;
    __syncthreads();
    // rotate the final 16-value sum across waves to avoid a fixed straggler.
    // Safe: next write to red[rb] is at t+2, >=2 barriers away.
    if (tid == ((t & 15) << 6)) {
      const float4 r0 = *(const float4*)(&red[rb][0]);
      const float4 r1 = *(const float4*)(&red[rb][4]);
      const float4 r2 = *(const float4*)(&red[rb][8]);
      const float4 r3 = *(const float4*)(&red[rb][12]);
      out[(size_t)b * T_ + t] = bl
          + r0.x + r0.y + r0.z + r0.w + r1.x + r1.y + r1.z + r1.w
          + r2.x + r2.y + r2.z + r2.w + r3.x + r3.y + r3.z + r3.w;
    }
  }
}

extern "C" void kernel_launch(void* const* d_in, const int* in_sizes, int n_in,
                              void* d_out, int out_size, void* d_ws, size_t ws_size,
                              hipStream_t stream) {
  // Zero-workspace design: d_ws deliberately unused.
  lstm_fused<<<B_, 1024, 0, stream>>>(
      (const float*)d_in[0],
      (const float*)d_in[1], (const float*)d_in[2],
      (const float*)d_in[3], (const float*)d_in[4],
      (const float*)d_in[5], (const float*)d_in[6],
      (const float*)d_in[7], (const float*)d_in[8],
      (const float*)d_in[9], (const float*)d_in[10],
      (float*)d_out);
}

// Round 5
// 1751.455 us; speedup vs baseline: 1.5438x; 1.5438x over previous
//
#include <hip/hip_runtime.h>
#include <hip/hip_fp16.h>

#define B_ 256
#define T_ 1200
#define I_ 16
#define H_ 128
#define G4_ (4 * H_)   // 512 gate rows per layer

typedef __attribute__((ext_vector_type(2))) _Float16 h2;
typedef __attribute__((ext_vector_type(8))) _Float16 f16x8;

union f16x8u { f16x8 v; h2 h[4]; _Float16 s[8]; };

#if __has_builtin(__builtin_amdgcn_fdot2)
__device__ __forceinline__ float fdot2(h2 a, h2 b, float c) {
  return __builtin_amdgcn_fdot2(a, b, c, false);  // v_dot2_f32_f16
}
#else
__device__ __forceinline__ float fdot2(h2 a, h2 b, float c) {
  return fmaf((float)a.x, (float)b.x, fmaf((float)a.y, (float)b.y, c));
}
#endif

// broadcast one quad lane to all 4 (DPP quad_perm).
// PAT must be a compile-time constant: 0x00/0x55/0xAA/0xFF.
template <int PAT>
__device__ __forceinline__ float qbcast(float x) {
  return __int_as_float(__builtin_amdgcn_update_dpp(0, __float_as_int(x), PAT, 0xF, 0xF, true));
}

// reduce quad-uniform values across the 16 quads of a wave
__device__ __forceinline__ float wred(float x) {
  x += __int_as_float(__builtin_amdgcn_update_dpp(0, __float_as_int(x), 0x141, 0xF, 0xF, true)); // row_half_mirror ~ xor4
  x += __int_as_float(__builtin_amdgcn_update_dpp(0, __float_as_int(x), 0x140, 0xF, 0xF, true)); // row_mirror ~ xor8
  x += __shfl_xor(x, 16);
  x += __shfl_xor(x, 32);
  return x;
}

__device__ __forceinline__ float sigm(float x) {
  return __builtin_amdgcn_rcpf(1.f + __expf(-x));
}
__device__ __forceinline__ float tanh_(float x) {
  return 1.f - 2.f * __builtin_amdgcn_rcpf(1.f + __expf(2.f * x));
}

// Load a 128-wide f32 weight row as 64 fp16x2 into regs.
__device__ __forceinline__ void load_row_h2(const float* __restrict__ p, h2* w) {
#pragma unroll
  for (int i = 0; i < 32; ++i) {
    const float4 v = *(const float4*)(p + 4 * i);
    w[2 * i].x     = (_Float16)v.x; w[2 * i].y     = (_Float16)v.y;
    w[2 * i + 1].x = (_Float16)v.z; w[2 * i + 1].y = (_Float16)v.w;
  }
}

// ---------------------------------------------------------------------------
// K1: layer-0 recurrence. 1 block per batch row, 512 thr.
// Thread owns gate-row g = q*128 + j (q=tid&3, j=tid>>2): full-row dot, no
// cross-lane reduce. Weights: 64+8 h2 in regs (fits the observed 128-reg cap).
// x[b] staged once in LDS as fp16 (38.4 KB). h0 state: LDS double buffer,
// ONE barrier per step. Gates gathered via 4 quad_perm broadcasts
// (quad lane index == gate index). Writes h0[b,t,:] fp16 to workspace.
// ---------------------------------------------------------------------------
__global__ __launch_bounds__(512, 2) void k1_layer0(
    const float* __restrict__ xin,
    const float* __restrict__ Wih0, const float* __restrict__ Whh0,
    const float* __restrict__ bih0, const float* __restrict__ bhh0,
    __half* __restrict__ h0ws)
{
  __shared__ __align__(16) __half xs[T_ * I_];   // 38400 B
  __shared__ __align__(16) __half hb[2][H_];

  const int tid = threadIdx.x;
  const int q = tid & 3;
  const int j = tid >> 2;
  const int g = q * H_ + j;
  const int b = blockIdx.x;

  // stage x[b] -> LDS fp16 (coalesced float4 reads)
  {
    const float4* xg4 = (const float4*)(xin + (size_t)b * T_ * I_);
    for (int idx = tid; idx < T_ * I_ / 4; idx += 512) {
      const float4 v = xg4[idx];
      xs[4 * idx]     = __float2half(v.x);
      xs[4 * idx + 1] = __float2half(v.y);
      xs[4 * idx + 2] = __float2half(v.z);
      xs[4 * idx + 3] = __float2half(v.w);
    }
  }

  h2 wh[64], wx[8];
  load_row_h2(Whh0 + (size_t)g * H_, wh);
  {
    const float* px = Wih0 + (size_t)g * I_;
#pragma unroll
    for (int i = 0; i < 4; ++i) {
      const float4 v = *(const float4*)(px + 4 * i);
      wx[2 * i].x     = (_Float16)v.x; wx[2 * i].y     = (_Float16)v.y;
      wx[2 * i + 1].x = (_Float16)v.z; wx[2 * i + 1].y = (_Float16)v.w;
    }
  }
  const float bs = bih0[g] + bhh0[g];

  if (tid < H_) hb[0][tid] = __float2half(0.f);
  float cst = 0.f;
  __half* h0o = h0ws + (size_t)b * T_ * H_ + j;
  __syncthreads();

#pragma unroll 2
  for (int t = 0; t < T_; ++t) {
    const int rb = t & 1;
    float a0 = 0.f, a1 = 0.f, a2 = 0.f, a3 = 0.f;
#pragma unroll
    for (int i = 0; i < 16; ++i) {                       // h_{t-1} dot (broadcast)
      f16x8u u; u.v = *(const f16x8*)(&hb[rb][8 * i]);
      a0 = fdot2(wh[4 * i],     u.h[0], a0);
      a1 = fdot2(wh[4 * i + 1], u.h[1], a1);
      a2 = fdot2(wh[4 * i + 2], u.h[2], a2);
      a3 = fdot2(wh[4 * i + 3], u.h[3], a3);
    }
#pragma unroll
    for (int m = 0; m < 2; ++m) {                        // x_t dot
      f16x8u u; u.v = *(const f16x8*)(&xs[t * I_ + 8 * m]);
      a0 = fdot2(wx[4 * m],     u.h[0], a0);
      a1 = fdot2(wx[4 * m + 1], u.h[1], a1);
      a2 = fdot2(wx[4 * m + 2], u.h[2], a2);
      a3 = fdot2(wx[4 * m + 3], u.h[3], a3);
    }
    const float pre = (a0 + a1) + (a2 + a3) + bs;        // this thread's gate q
    // gather the quad's 4 gates (lane index == gate index)
    const float ip = qbcast<0x00>(pre);
    const float fp = qbcast<0x55>(pre);
    const float gp = qbcast<0xAA>(pre);
    const float op = qbcast<0xFF>(pre);
    const float ig = sigm(ip), fg = sigm(fp), gg = tanh_(gp), og = sigm(op);
    cst = fg * cst + ig * gg;
    const float hv = og * tanh_(cst);
    const __half hh = __float2half(hv);
    if (q == 0) {
      hb[rb ^ 1][j] = hh;
      h0o[(size_t)t * H_] = hh;
    }
    __syncthreads();
  }
}

// ---------------------------------------------------------------------------
// K2: pre1[b,t,g] = W_ih1[g,:] . h0[b,t,:]  (no recurrence, no barriers).
// 1 block per batch row, 512 thr, thread = gate-row g. h0 rows are broadcast
// global loads (all lanes same line -> L1). Fully compiler-pipelineable.
// ---------------------------------------------------------------------------
__global__ __launch_bounds__(512, 2) void k2_pregemm(
    const __half* __restrict__ h0ws,
    const float* __restrict__ Wih1,
    __half* __restrict__ pre1)
{
  const int g = threadIdx.x;
  const int b = blockIdx.x;

  h2 w[64];
  load_row_h2(Wih1 + (size_t)g * H_, w);

  const __half* hrow = h0ws + (size_t)b * T_ * H_;
  __half* pp = pre1 + (size_t)b * T_ * G4_ + g;

#pragma unroll 2
  for (int t = 0; t < T_; ++t) {
    const __half* hr = hrow + (size_t)t * H_;
    float a0 = 0.f, a1 = 0.f, a2 = 0.f, a3 = 0.f;
#pragma unroll
    for (int i = 0; i < 16; ++i) {
      f16x8u u; u.v = *(const f16x8*)(hr + 8 * i);
      a0 = fdot2(w[4 * i],     u.h[0], a0);
      a1 = fdot2(w[4 * i + 1], u.h[1], a1);
      a2 = fdot2(w[4 * i + 2], u.h[2], a2);
      a3 = fdot2(w[4 * i + 3], u.h[3], a3);
    }
    pp[(size_t)t * G4_] = __float2half((a0 + a1) + (a2 + a3));
  }
}

// ---------------------------------------------------------------------------
// K3: layer-1 recurrence + relu + W_lin head. 1 block per batch row, 512 thr.
// Thread owns gate-row g: W_hh1 row (64 h2) in regs; ih-contribution arrives
// as ONE coalesced fp16 load/thread/step (prefetched one step ahead).
// Quad-gate cell as in K1; fused head reduce (wred + per-wave LDS + rotation).
// ---------------------------------------------------------------------------
__global__ __launch_bounds__(512, 2) void k3_layer1(
    const __half* __restrict__ pre1,
    const float* __restrict__ Whh1,
    const float* __restrict__ bih1, const float* __restrict__ bhh1,
    const float* __restrict__ Wlin, const float* __restrict__ blin,
    float* __restrict__ out)
{
  __shared__ __align__(16) __half hb[2][H_];
  __shared__ __align__(16) float red[2][8];

  const int tid = threadIdx.x;
  const int q = tid & 3;
  const int j = tid >> 2;
  const int g = q * H_ + j;
  const int b = blockIdx.x;
  const int wv = tid >> 6;

  h2 w[64];
  load_row_h2(Whh1 + (size_t)g * H_, w);
  const float bs = bih1[g] + bhh1[g];
  const float wl = Wlin[j];   // quad-uniform use; wred sums quads only
  const float bl = blin[0];

  if (tid < H_) hb[0][tid] = __float2half(0.f);
  float cst = 0.f;
  const __half* pp = pre1 + (size_t)b * T_ * G4_ + g;
  float* op = out + (size_t)b * T_;
  __syncthreads();

  __half pnext = pp[0];
#pragma unroll 2
  for (int t = 0; t < T_; ++t) {
    const int rb = t & 1;
    const __half pcur = pnext;
    if (t + 1 < T_) pnext = pp[(size_t)(t + 1) * G4_];   // prefetch
    float a0 = 0.f, a1 = 0.f, a2 = 0.f, a3 = 0.f;
#pragma unroll
    for (int i = 0; i < 16; ++i) {                        // h1_{t-1} dot
      f16x8u u; u.v = *(const f16x8*)(&hb[rb][8 * i]);
      a0 = fdot2(w[4 * i],     u.h[0], a0);
      a1 = fdot2(w[4 * i + 1], u.h[1], a1);
      a2 = fdot2(w[4 * i + 2], u.h[2], a2);
      a3 = fdot2(w[4 * i + 3], u.h[3], a3);
    }
    const float pre = (a0 + a1) + (a2 + a3) + __half2float(pcur) + bs;
    const float ip = qbcast<0x00>(pre);
    const float fp = qbcast<0x55>(pre);
    const float gp = qbcast<0xAA>(pre);
    const float op_ = qbcast<0xFF>(pre);
    const float ig = sigm(ip), fg = sigm(fp), gg = tanh_(gp), og = sigm(op_);
    cst = fg * cst + ig * gg;
    const float hv = og * tanh_(cst);
    if (q == 0) hb[rb ^ 1][j] = __float2half(hv);
    // head: relu + W_lin (quad-uniform -> reduce 16 quads, then 8 waves)
    float val = wred(fmaxf(hv, 0.f) * wl);
    if ((tid & 63) == 0) red[rb][wv] = val;
    __syncthreads();
    // rotate the reader to avoid a fixed straggler; red[rb] rewritten at t+2,
    // which is >= 2 barriers away.
    if (tid == ((t & 7) << 6)) {
      const float4 r0 = *(const float4*)(&red[rb][0]);
      const float4 r1 = *(const float4*)(&red[rb][4]);
      op[t] = bl + r0.x + r0.y + r0.z + r0.w + r1.x + r1.y + r1.z + r1.w;
    }
  }
}

// ---------------------------------------------------------------------------
// Fallback: round-1 fused kernel (known-good, 1752 us) if workspace is small.
// ---------------------------------------------------------------------------
__device__ __forceinline__ float qsum8f(float x) {
  x += __int_as_float(__builtin_amdgcn_update_dpp(0, __float_as_int(x), 0xB1, 0xF, 0xF, true));
  x += __int_as_float(__builtin_amdgcn_update_dpp(0, __float_as_int(x), 0x4E, 0xF, 0xF, true));
  return x;
}

__global__ __launch_bounds__(512, 2) void lstm_fused_fb(
    const float* __restrict__ xin,
    const float* __restrict__ Wih0, const float* __restrict__ Whh0,
    const float* __restrict__ bih0, const float* __restrict__ bhh0,
    const float* __restrict__ Wih1, const float* __restrict__ Whh1,
    const float* __restrict__ bih1, const float* __restrict__ bhh1,
    const float* __restrict__ Wlin, const float* __restrict__ blin,
    float* __restrict__ out)
{
  __shared__ __align__(16) __half buf0[2][H_];
  __shared__ __align__(16) __half buf1[2][H_];
  __shared__ __align__(16) float red[2][8];

  const int tid = threadIdx.x;
  const int c = tid & 3;
  const int j = tid >> 2;
  const int b = blockIdx.x;
  const int wv = tid >> 6;

  h2 w0[4][16], wi[4][16], wh[4][16];
  h2 wx[4][2];
  float bs0[4], bs1[4];

#pragma unroll
  for (int qq = 0; qq < 4; ++qq) {
    const int g = qq * H_ + j;
    const float* p0 = Whh0 + (size_t)g * H_ + c * 32;
    const float* p1 = Wih1 + (size_t)g * H_ + c * 32;
    const float* p2 = Whh1 + (size_t)g * H_ + c * 32;
#pragma unroll
    for (int i = 0; i < 8; ++i) {
      float4 v = *(const float4*)(p0 + 4 * i);
      w0[qq][2*i].x   = (_Float16)v.x; w0[qq][2*i].y   = (_Float16)v.y;
      w0[qq][2*i+1].x = (_Float16)v.z; w0[qq][2*i+1].y = (_Float16)v.w;
      v = *(const float4*)(p1 + 4 * i);
      wi[qq][2*i].x   = (_Float16)v.x; wi[qq][2*i].y   = (_Float16)v.y;
      wi[qq][2*i+1].x = (_Float16)v.z; wi[qq][2*i+1].y = (_Float16)v.w;
      v = *(const float4*)(p2 + 4 * i);
      wh[qq][2*i].x   = (_Float16)v.x; wh[qq][2*i].y   = (_Float16)v.y;
      wh[qq][2*i+1].x = (_Float16)v.z; wh[qq][2*i+1].y = (_Float16)v.w;
    }
    const float4 vx = *(const float4*)(Wih0 + (size_t)g * I_ + 4 * c);
    wx[qq][0].x = (_Float16)vx.x; wx[qq][0].y = (_Float16)vx.y;
    wx[qq][1].x = (_Float16)vx.z; wx[qq][1].y = (_Float16)vx.w;
    bs0[qq] = bih0[g] + bhh0[g];
    bs1[qq] = bih1[g] + bhh1[g];
  }
  const float wl = Wlin[j];
  const float bl = blin[0];

  if (tid < H_) {
    buf0[0][tid] = __float2half(0.f);
    buf1[0][tid] = __float2half(0.f);
  }
  float cst0 = 0.f, cst1 = 0.f;
  const float* xp = xin + (size_t)b * T_ * I_ + 4 * c;
  float* op = out + (size_t)b * T_;
  __syncthreads();

#pragma unroll 2
  for (int t = 0; t < T_; ++t) {
    const int rb = t & 1;
    const float4 xv = *(const float4*)xp; xp += I_;
    float a0 = 0.f, a1 = 0.f, a2 = 0.f, a3 = 0.f;
#pragma unroll
    for (int i = 0; i < 4; ++i) {
      f16x8u u; u.v = *(const f16x8*)(&buf0[rb][c * 32 + i * 8]);
#pragma unroll
      for (int p = 0; p < 4; ++p) {
        const h2 hv = u.h[p];
        a0 = fdot2(w0[0][4 * i + p], hv, a0);
        a1 = fdot2(w0[1][4 * i + p], hv, a1);
        a2 = fdot2(w0[2][4 * i + p], hv, a2);
        a3 = fdot2(w0[3][4 * i + p], hv, a3);
      }
    }
    h2 xa, xb;
    xa.x = (_Float16)xv.x; xa.y = (_Float16)xv.y;
    xb.x = (_Float16)xv.z; xb.y = (_Float16)xv.w;
    a0 = fdot2(wx[0][0], xa, fdot2(wx[0][1], xb, a0));
    a1 = fdot2(wx[1][0], xa, fdot2(wx[1][1], xb, a1));
    a2 = fdot2(wx[2][0], xa, fdot2(wx[2][1], xb, a2));
    a3 = fdot2(wx[3][0], xa, fdot2(wx[3][1], xb, a3));
    {
      const float g0 = qsum8f(a0) + bs0[0];
      const float g1 = qsum8f(a1) + bs0[1];
      const float g2 = qsum8f(a2) + bs0[2];
      const float g3 = qsum8f(a3) + bs0[3];
      const float ig = sigm(g0), fg = sigm(g1), gg = tanh_(g2), og = sigm(g3);
      cst0 = fg * cst0 + ig * gg;
      const float h0v = og * tanh_(cst0);
      if (c == 0) buf0[rb ^ 1][j] = __float2half(h0v);
    }
    __syncthreads();
    a0 = 0.f; a1 = 0.f; a2 = 0.f; a3 = 0.f;
#pragma unroll
    for (int i = 0; i < 4; ++i) {
      f16x8u u; u.v = *(const f16x8*)(&buf0[rb ^ 1][c * 32 + i * 8]);
#pragma unroll
      for (int p = 0; p < 4; ++p) {
        const h2 hv = u.h[p];
        a0 = fdot2(wi[0][4 * i + p], hv, a0);
        a1 = fdot2(wi[1][4 * i + p], hv, a1);
        a2 = fdot2(wi[2][4 * i + p], hv, a2);
        a3 = fdot2(wi[3][4 * i + p], hv, a3);
      }
    }
#pragma unroll
    for (int i = 0; i < 4; ++i) {
      f16x8u u; u.v = *(const f16x8*)(&buf1[rb][c * 32 + i * 8]);
#pragma unroll
      for (int p = 0; p < 4; ++p) {
        const h2 hv = u.h[p];
        a0 = fdot2(wh[0][4 * i + p], hv, a0);
        a1 = fdot2(wh[1][4 * i + p], hv, a1);
        a2 = fdot2(wh[2][4 * i + p], hv, a2);
        a3 = fdot2(wh[3][4 * i + p], hv, a3);
      }
    }
    const float g0 = qsum8f(a0) + bs1[0];
    const float g1 = qsum8f(a1) + bs1[1];
    const float g2 = qsum8f(a2) + bs1[2];
    const float g3 = qsum8f(a3) + bs1[3];
    const float ig = sigm(g0), fg = sigm(g1), gg = tanh_(g2), og = sigm(g3);
    cst1 = fg * cst1 + ig * gg;
    const float h1v = og * tanh_(cst1);
    if (c == 0) buf1[rb ^ 1][j] = __float2half(h1v);
    float val = wred(fmaxf(h1v, 0.f) * wl);
    if ((tid & 63) == 0) red[rb][wv] = val;
    __syncthreads();
    if (tid == ((t & 7) << 6)) {
      const float4 r0 = *(const float4*)(&red[rb][0]);
      const float4 r1 = *(const float4*)(&red[rb][4]);
      op[t] = bl + r0.x + r0.y + r0.z + r0.w + r1.x + r1.y + r1.z + r1.w;
    }
  }
}

extern "C" void kernel_launch(void* const* d_in, const int* in_sizes, int n_in,
                              void* d_out, int out_size, void* d_ws, size_t ws_size,
                              hipStream_t stream) {
  const size_t H0_BYTES  = (size_t)B_ * T_ * H_ * sizeof(__half);        // 78.6 MB
  const size_t PRE_BYTES = (size_t)B_ * T_ * G4_ * sizeof(__half);       // 314.6 MB

  if (d_ws != nullptr && ws_size >= H0_BYTES + PRE_BYTES) {
    __half* h0ws = (__half*)d_ws;
    __half* pre1 = (__half*)((char*)d_ws + H0_BYTES);
    k1_layer0<<<B_, 512, 0, stream>>>(
        (const float*)d_in[0],
        (const float*)d_in[1], (const float*)d_in[2],
        (const float*)d_in[3], (const float*)d_in[4],
        h0ws);
    k2_pregemm<<<B_, 512, 0, stream>>>(
        h0ws, (const float*)d_in[5], pre1);
    k3_layer1<<<B_, 512, 0, stream>>>(
        pre1, (const float*)d_in[6],
        (const float*)d_in[7], (const float*)d_in[8],
        (const float*)d_in[9], (const float*)d_in[10],
        (float*)d_out);
  } else {
    lstm_fused_fb<<<B_, 512, 0, stream>>>(
        (const float*)d_in[0],
        (const float*)d_in[1], (const float*)d_in[2],
        (const float*)d_in[3], (const float*)d_in[4],
        (const float*)d_in[5], (const float*)d_in[6],
        (const float*)d_in[7], (const float*)d_in[8],
        (const float*)d_in[9], (const float*)d_in[10],
        (float*)d_out);
  }
}